// Round 1
// baseline (392.878 us; speedup 1.0000x reference)
//
#include <hip/hip_runtime.h>
#include <cmath>

#define BATCH 32768
#define TLEN  1024
// NF = 513, NF-1 = 512

__device__ __forceinline__ int brev10(int p) {
    return (int)(__brev((unsigned)p) >> 22);
}

// Nearest frequency bin to `target`, replicating JAX fp32 argmin(|freq - target|)
// with first-occurrence tie-break. freq(i) = (fs*0.5f) * (i/512.0f).
__device__ __forceinline__ int nearest_bin(float fs, float target) {
    float x = target * 1024.0f / fs;     // approximate real-valued bin
    int i0 = (int)floorf(x);
    int lo = max(0, i0 - 1), hi = min(512, i0 + 2);
    int bi = lo; float bd = 1e30f;
    for (int i = lo; i <= hi; ++i) {     // ascending + strict < == first-min tie-break
        float fr = (fs * 0.5f) * ((float)i / 512.0f);
        float d = fabsf(fr - target);
        if (d < bd) { bd = d; bi = i; }
    }
    return bi;
}

__global__ __launch_bounds__(256) void fft_loss_kernel(
    const float* __restrict__ preds, const float* __restrict__ Fs,
    float* __restrict__ partial)
{
    __shared__ float re[1024];
    __shared__ float im[1024];
    __shared__ float twr[512];
    __shared__ float twi[512];
    __shared__ float w_tot[4], w_inb[4], w_best[4];
    __shared__ int   w_besti[4];

    const int row = blockIdx.x;
    const int tid = threadIdx.x;
    const float* x = preds + (size_t)row * TLEN;

    // Load input (coalesced) and build twiddle table tw[k] = exp(-2*pi*i*k/1024)
    #pragma unroll
    for (int i = tid; i < 1024; i += 256) { re[i] = x[i]; im[i] = 0.0f; }
    #pragma unroll
    for (int k = tid; k < 512; k += 256) {
        float ang = -(float)k * (float)(M_PI / 512.0);
        float s, c;
        sincosf(ang, &s, &c);
        twr[k] = c; twi[k] = s;
    }
    __syncthreads();

    // Radix-2 DIF FFT: natural-order input, bit-reversed output.
    // Stage s: m = 2^s, half = m/2; butterfly: x[i0] = u+v; x[i1] = (u-v)*w_m^j
    for (int s = 10; s >= 1; --s) {
        const int half = 1 << (s - 1);
        #pragma unroll
        for (int b = tid; b < 512; b += 256) {
            const int j   = b & (half - 1);
            const int grp = b >> (s - 1);
            const int i0  = (grp << s) + j;
            const int i1  = i0 + half;
            const int t   = j << (10 - s);
            float ur = re[i0], ui = im[i0];
            float vr = re[i1], vi = im[i1];
            float dr = ur - vr, di = ui - vi;
            float wr = twr[t],  wi = twi[t];
            re[i0] = ur + vr;  im[i0] = ui + vi;
            re[i1] = dr * wr - di * wi;
            im[i1] = dr * wi + di * wr;
        }
        __syncthreads();
    }

    // Per-row band parameters (uniform across threads)
    const float fs = Fs[row];
    const int left  = nearest_bin(fs, (float)(40.0 / 60.0));
    const int right = nearest_bin(fs, (float)(180.0 / 60.0));

    // Strided reduction over storage positions; f = brev10(p) is the freq bin.
    float total = 0.0f, inb = 0.0f, best = -1.0f;
    int besti = 0x7fffffff;
    #pragma unroll
    for (int p = tid; p < 1024; p += 256) {
        const int f = brev10(p);
        if (f > 512) continue;
        float vr = re[p], vi = im[p];
        float v = vr * vr + vi * vi;
        total += v;
        if (f >= left && f < right) {
            inb += v;
            if (v > best || (v == best && f < besti)) { best = v; besti = f; }
        }
    }

    // Wave (64-lane) reduce, then cross-wave via LDS.
    const int lane = tid & 63, wv = tid >> 6;
    for (int off = 32; off > 0; off >>= 1) {
        total += __shfl_down(total, off);
        inb   += __shfl_down(inb, off);
        float ob = __shfl_down(best, off);
        int   oi = __shfl_down(besti, off);
        if (ob > best || (ob == best && oi < besti)) { best = ob; besti = oi; }
    }
    if (lane == 0) { w_tot[wv] = total; w_inb[wv] = inb; w_best[wv] = best; w_besti[wv] = besti; }
    __syncthreads();

    if (tid == 0) {
        float T = 0.0f, I = 0.0f, Bst = -1.0f; int Bi = 0x7fffffff;
        for (int w = 0; w < 4; ++w) {
            T += w_tot[w]; I += w_inb[w];
            if (w_best[w] > Bst || (w_best[w] == Bst && w_besti[w] < Bi)) {
                Bst = w_best[w]; Bi = w_besti[w];
            }
        }
        // delta = max(1, round(DELTA_HZ / (Fs*0.5/NF))), NF = 513, DELTA_HZ = 0.1
        int delta = (int)rintf(0.1f / ((fs * 0.5f) / 513.0f));
        if (delta < 1) delta = 1;
        // Peak-window sum over in-band bins in [Bi-delta, Bi+delta)
        int lo = max(left, Bi - delta), hi = min(right, Bi + delta);
        float wsum = 0.0f;
        for (int f = lo; f < hi; ++f) {
            int p = brev10(f);
            float vr = re[p], vi = im[p];
            wsum += vr * vr + vi * vi;
        }
        float band_loss   = (T - I) / (1e-8f + T);
        float den         = I + 1e-8f * (float)(right - left);
        float sparse_loss = (I - wsum) / den;
        partial[row] = band_loss + sparse_loss;
    }
}

__global__ __launch_bounds__(256) void reduce_kernel(
    const float* __restrict__ partial, float* __restrict__ out)
{
    __shared__ float w[4];
    float acc = 0.0f;
    for (int i = threadIdx.x; i < BATCH; i += 256) acc += partial[i];
    for (int off = 32; off > 0; off >>= 1) acc += __shfl_down(acc, off);
    const int lane = threadIdx.x & 63, wv = threadIdx.x >> 6;
    if (lane == 0) w[wv] = acc;
    __syncthreads();
    if (threadIdx.x == 0) out[0] = (w[0] + w[1] + w[2] + w[3]) * (1.0f / (float)BATCH);
}

extern "C" void kernel_launch(void* const* d_in, const int* in_sizes, int n_in,
                              void* d_out, int out_size, void* d_ws, size_t ws_size,
                              hipStream_t stream) {
    const float* preds = (const float*)d_in[0];
    const float* Fs    = (const float*)d_in[1];
    float* partial     = (float*)d_ws;   // BATCH floats = 128 KB scratch
    float* out         = (float*)d_out;

    fft_loss_kernel<<<BATCH, 256, 0, stream>>>(preds, Fs, partial);
    reduce_kernel<<<1, 256, 0, stream>>>(partial, out);
}

// Round 2
// 191.325 us; speedup vs baseline: 2.0535x; 2.0535x over previous
//
#include <hip/hip_runtime.h>
#include <cmath>

#define BATCH 32768

struct cplx { float x, y; };
__device__ __forceinline__ cplx cadd(cplx a, cplx b){ return {a.x+b.x, a.y+b.y}; }
__device__ __forceinline__ cplx csub(cplx a, cplx b){ return {a.x-b.x, a.y-b.y}; }
__device__ __forceinline__ cplx cmul(cplx a, cplx b){ return {a.x*b.x - a.y*b.y, a.x*b.y + a.y*b.x}; }
__device__ __forceinline__ cplx cmul_mi(cplx a){ return {a.y, -a.x}; }                 // a * (-i)
__device__ __forceinline__ cplx cmul_w81(cplx a){ const float c=0.70710678f; return {c*(a.x+a.y), c*(a.y-a.x)}; } // a*W8^1
__device__ __forceinline__ cplx cmul_w83(cplx a){ const float c=0.70710678f; return {c*(a.y-a.x), -c*(a.x+a.y)}; } // a*W8^3

// 8-point DFT, natural-order in/out: A_r = sum_m a_m * W8^{r m}
__device__ __forceinline__ void dft8(cplx a[8]) {
    cplx t0=cadd(a[0],a[4]), t4=csub(a[0],a[4]);
    cplx t1=cadd(a[1],a[5]), t5=csub(a[1],a[5]);
    cplx t2=cadd(a[2],a[6]), t6=csub(a[2],a[6]);
    cplx t3=cadd(a[3],a[7]), t7=csub(a[3],a[7]);
    cplx u0=cadd(t0,t2), u2=csub(t0,t2);
    cplx u1=cadd(t1,t3), u3=cmul_mi(csub(t1,t3));
    a[0]=cadd(u0,u1); a[4]=csub(u0,u1); a[2]=cadd(u2,u3); a[6]=csub(u2,u3);
    cplx v0=t4, v1=cmul_w81(t5), v2=cmul_mi(t6), v3=cmul_w83(t7);
    cplx w0=cadd(v0,v2), w2=csub(v0,v2);
    cplx w1=cadd(v1,v3), w3=cmul_mi(csub(v1,v3));
    a[1]=cadd(w0,w1); a[5]=csub(w0,w1); a[3]=cadd(w2,w3); a[7]=csub(w2,w3);
}

// Replicates JAX fp32 argmin(|freq - target|), first-occurrence tie-break.
__device__ __forceinline__ int nearest_bin(float fs, float target) {
    float x = target * 1024.0f / fs;
    int i0 = (int)floorf(x);
    int lo = max(0, i0 - 1), hi = min(512, i0 + 2);
    int bi = lo; float bd = 1e30f;
    for (int i = lo; i <= hi; ++i) {
        float fr = (fs * 0.5f) * ((float)i / 512.0f);
        float d = fabsf(fr - target);
        if (d < bd) { bd = d; bi = i; }
    }
    return bi;
}

// One wave (64 lanes) per row. 512-pt complex FFT of packed even/odd samples
// (radix 8x8x8, register DFT-8s, intra-wave LDS transposes), then rfft combine.
__global__ __launch_bounds__(256) void fft_loss_kernel(
    const float* __restrict__ preds, const float* __restrict__ Fs,
    float* __restrict__ blockpartial)
{
    __shared__ float sre[4][576];   // per-wave: 8 rows x stride 72 (conflict-free)
    __shared__ float sim[4][576];
    __shared__ float sblk[4];

    const int tid  = threadIdx.x;
    const int wv   = tid >> 6;
    const int lane = tid & 63;
    const int row  = blockIdx.x * 4 + wv;

    float* re = sre[wv];
    float* im = sim[wv];

    // z[n] = x[2n] + i*x[2n+1] == float2 view of the row.
    const float2* x2 = reinterpret_cast<const float2*>(preds) + (size_t)row * 512;

    // ---- Stage A: lane = n0; DFT8 over n1 (stride-64 elements) ----
    cplx z[8];
#pragma unroll
    for (int n1 = 0; n1 < 8; ++n1) {
        float2 v = x2[n1 * 64 + lane];
        z[n1] = {v.x, v.y};
    }
    dft8(z);
    {   // twiddle W_512^{r*n0} via recurrence from W_512^{n0}
        float sb, cb;
        __sincosf(-0.012271846f * (float)lane, &sb, &cb);   // -2pi/512 * lane
        cplx w = {cb, sb}, u = w;
#pragma unroll
        for (int r = 1; r < 8; ++r) { z[r] = cmul(z[r], u); u = cmul(u, w); }
    }
#pragma unroll
    for (int r = 0; r < 8; ++r) { re[r*72 + lane] = z[r].x; im[r*72 + lane] = z[r].y; }

    // ---- Stage B: lane = (r, m0); DFT8 over m1 ----
    const int rB = lane & 7, m0 = lane >> 3;
    cplx b[8];
#pragma unroll
    for (int m1 = 0; m1 < 8; ++m1) {
        int a = rB*72 + 8*m1 + m0;
        b[m1] = {re[a], im[a]};
    }
    dft8(b);
    {   // twiddle W_64^{s*m0}
        float sb, cb;
        __sincosf(-0.09817477f * (float)m0, &sb, &cb);      // -2pi/64 * m0
        cplx w = {cb, sb}, u = w;
#pragma unroll
        for (int s = 1; s < 8; ++s) { b[s] = cmul(b[s], u); u = cmul(u, w); }
    }
#pragma unroll
    for (int s = 0; s < 8; ++s) {   // XOR-swizzled 8x8 transpose (2-way banks both sides)
        int a = rB*72 + 8*m0 + ((s + m0) & 7);
        re[a] = b[s].x; im[a] = b[s].y;
    }

    // ---- Stage C: lane = (r, s); DFT8 over m0 -> Z[lane + 64 t] ----
    const int sC = lane >> 3;
    cplx c[8];
#pragma unroll
    for (int m = 0; m < 8; ++m) {
        int a = rB*72 + 8*m + ((sC + m) & 7);
        c[m] = {re[a], im[a]};
    }
    dft8(c);
#pragma unroll
    for (int t = 0; t < 8; ++t) { re[lane + 64*t] = c[t].x; im[lane + 64*t] = c[t].y; }

    // ---- rfft combine: X[k] = E + W_1024^k * O, psd = |X|^2 ----
    const float fs  = Fs[row];
    const int left  = nearest_bin(fs, (float)(40.0/60.0));
    const int right = nearest_bin(fs, 3.0f);

    float psd[8];
    float total = 0.f, inb = 0.f, best = -1.f;
    int besti = 1 << 30;
    float sk, ck;
    __sincosf(-0.0061359233f * (float)lane, &sk, &ck);      // -2pi/1024 * lane
    cplx wk = {ck, sk};
    const cplx wstep = {0.92387953f, -0.38268343f};         // W_1024^64 = W_16
#pragma unroll
    for (int t = 0; t < 8; ++t) {
        int k  = lane + 64*t;
        cplx a  = {re[k], im[k]};
        int k2 = (512 - k) & 511;
        cplx bb = {re[k2], -im[k2]};
        float ex = 0.5f*(a.x + bb.x), ey = 0.5f*(a.y + bb.y);
        float dx = a.x - bb.x,        dy = a.y - bb.y;
        float ox = 0.5f*dy,           oy = -0.5f*dx;
        float Xr = ex + wk.x*ox - wk.y*oy;
        float Xi = ey + wk.x*oy + wk.y*ox;
        float v  = Xr*Xr + Xi*Xi;
        psd[t] = v;
        total += v;
        if (k >= left && k < right) {
            inb += v;
            if (v > best) { best = v; besti = k; }
        }
        wk = cmul(wk, wstep);
    }
    float psd512 = 0.f;
    if (lane == 0) {                  // Nyquist bin k=512 (never in band)
        float d = re[0] - im[0];
        psd512 = d*d;
        total += psd512;
    }
    // store psd AFTER all Z reads are done (separate loop = safe ordering)
#pragma unroll
    for (int t = 0; t < 8; ++t) im[lane + 64*t] = psd[t];
    if (lane == 0) im[512] = psd512;

    // ---- wave reduce: sums + argmax (min-index tie-break) ----
#pragma unroll
    for (int off = 32; off > 0; off >>= 1) {
        total += __shfl_down(total, off);
        inb   += __shfl_down(inb, off);
        float ob = __shfl_down(best, off);
        int   oi = __shfl_down(besti, off);
        if (ob > best || (ob == best && oi < besti)) { best = ob; besti = oi; }
    }
    if (lane == 0) {
        int delta = (int)rintf(0.1f / ((fs * 0.5f) / 513.0f));
        if (delta < 1) delta = 1;                       // delta in {3,4} for fs in [25,35)
        int lo = max(left, besti - delta), hi = min(right, besti + delta);
        float wsum = 0.f;
        for (int f = lo; f < hi; ++f) wsum += im[f];
        float band = (total - inb) / (1e-8f + total);
        float den  = inb + 1e-8f * (float)(right - left);
        sblk[wv] = band + (inb - wsum) / den;
    }
    __syncthreads();
    if (tid == 0) blockpartial[blockIdx.x] = sblk[0] + sblk[1] + sblk[2] + sblk[3];
}

__global__ __launch_bounds__(1024) void reduce_kernel(
    const float* __restrict__ bp, float* __restrict__ out)
{
    __shared__ float w[16];
    const int t = threadIdx.x;
    float acc = 0.f;
#pragma unroll
    for (int i = 0; i < 8; ++i) acc += bp[t + 1024*i];
    for (int off = 32; off > 0; off >>= 1) acc += __shfl_down(acc, off);
    const int lane = t & 63, wvi = t >> 6;
    if (lane == 0) w[wvi] = acc;
    __syncthreads();
    if (t == 0) {
        float s = 0.f;
        for (int i = 0; i < 16; ++i) s += w[i];
        out[0] = s * (1.0f / (float)BATCH);
    }
}

extern "C" void kernel_launch(void* const* d_in, const int* in_sizes, int n_in,
                              void* d_out, int out_size, void* d_ws, size_t ws_size,
                              hipStream_t stream) {
    const float* preds = (const float*)d_in[0];
    const float* Fs    = (const float*)d_in[1];
    float* bp          = (float*)d_ws;      // 8192 floats = 32 KB
    float* out         = (float*)d_out;

    fft_loss_kernel<<<BATCH / 4, 256, 0, stream>>>(preds, Fs, bp);
    reduce_kernel<<<1, 1024, 0, stream>>>(bp, out);
}